// Round 5
// baseline (1711.132 us; speedup 1.0000x reference)
//
#include <hip/hip_runtime.h>
#include <hip/hip_bf16.h>

typedef __hip_bfloat16 bf16;
typedef __attribute__((ext_vector_type(8))) short bf16x8;
typedef __attribute__((ext_vector_type(4))) float f32x4;

#define B_     16
#define N_     1569
#define DIM_   768
#define NHEADS 8
#define HD_    96
#define LK_    393
#define LKP_   448
#define T0_    8
#define H0_    14
#define W0_    14

struct __align__(8) bf16x4s { bf16 a, b, c, d; };

// ----------------------------------------------------- fp32 -> bf16 convert
__global__ __launch_bounds__(256) void cvt_f32_bf16(
    const float* __restrict__ in, bf16* __restrict__ out, int n4) {
  int i = blockIdx.x * 256 + threadIdx.x;
  if (i < n4) {
    float4 v = ((const float4*)in)[i];
    bf16x4s o{__float2bfloat16(v.x), __float2bfloat16(v.y),
              __float2bfloat16(v.z), __float2bfloat16(v.w)};
    ((bf16x4s*)out)[i] = o;
  }
}

// ------------------------------------------- transpose fp32 in -> bf16 out
__global__ __launch_bounds__(256) void transpose_f32_bf16(
    const float* __restrict__ in, bf16* __restrict__ out, int R, int C) {
  __shared__ float tile[32][33];
  int c0 = blockIdx.x * 32, r0 = blockIdx.y * 32;
  int tx = threadIdx.x, ty = threadIdx.y;  // 32 x 8
  for (int i = 0; i < 32; i += 8) {
    int r = r0 + ty + i, c = c0 + tx;
    if (r < R && c < C) tile[ty + i][tx] = in[(size_t)r * C + c];
  }
  __syncthreads();
  for (int i = 0; i < 32; i += 8) {
    int c = c0 + ty + i, r = r0 + tx;
    if (c < C && r < R) out[(size_t)c * R + r] = __float2bfloat16(tile[tx][ty + i]);
  }
}

// --------------------------- pool-weight transpose: [96][27] -> [27][96] x3
__global__ __launch_bounds__(256) void prep_pw(
    const float* __restrict__ wq, const float* __restrict__ wk,
    const float* __restrict__ wv, float* __restrict__ outp) {
  int i = blockIdx.x * 256 + threadIdx.x;
  if (i < 2592) {
    int widx = i / 96, x = i % 96;
    outp[i]        = wq[x * 27 + widx];
    outp[2592 + i] = wk[x * 27 + widx];
    outp[5184 + i] = wv[x * 27 + widx];
  }
}

// ------------------- V transpose: [bh][393][96] -> [bh][96][448] (zero pad)
__global__ __launch_bounds__(256) void transpose_v(
    const bf16* __restrict__ in, bf16* __restrict__ out) {
  __shared__ bf16 t[32][33];
  const int bh = blockIdx.z;
  const int k0 = blockIdx.x * 32, d0 = blockIdx.y * 32;
  const bf16* ib = in + (size_t)bh * LK_ * HD_;
  bf16* ob = out + (size_t)bh * HD_ * LKP_;
  int tx = threadIdx.x, ty = threadIdx.y;  // 32 x 8
  for (int i = 0; i < 32; i += 8) {
    int k = k0 + ty + i, d = d0 + tx;  // d always < 96
    t[ty + i][tx] = (k < LK_) ? ib[(size_t)k * HD_ + d] : __float2bfloat16(0.f);
  }
  __syncthreads();
  for (int i = 0; i < 32; i += 8) {
    int d = d0 + ty + i, k = k0 + tx;  // k < 448 by grid
    ob[(size_t)d * LKP_ + k] = t[tx][ty + i];
  }
}

// ------------------------------------------------------- MFMA GEMM, C=A*BT^T
__device__ __forceinline__ void gl_lds16(const bf16* g, bf16* l) {
  __builtin_amdgcn_global_load_lds(
      (const __attribute__((address_space(1))) void*)g,
      (__attribute__((address_space(3))) void*)l, 16, 0, 0);
}

template <typename OutT>
__global__ __launch_bounds__(256) void gemm_bt(
    const bf16* __restrict__ A, const bf16* __restrict__ BT,
    const float* __restrict__ bias, OutT* __restrict__ C,
    int M, int Nn, int K) {
  constexpr int BM = 128, BN = 128, BK = 32;
  __shared__ __align__(16) bf16 As[BM][BK];
  __shared__ __align__(16) bf16 Bs[BN][BK];
  const int tid = threadIdx.x;
  const int lane = tid & 63, wave = tid >> 6;
  // grid: x = bn (small, fast), y = bm  -> consecutive blocks share A-tile,
  // keep whole B (<=3.5 MB) L2-resident instead of sweeping A past L2.
  const int bm = blockIdx.y * BM, bn = blockIdx.x * BN;
  const int wm = (wave >> 1) * 64, wn = (wave & 1) * 64;
  const int lrow = lane >> 2;       // 0..15
  const int lcol = (lane & 3) * 8;  // element offset (8 bf16 = 16B)

  f32x4 acc[4][4];
#pragma unroll
  for (int i = 0; i < 4; ++i)
#pragma unroll
    for (int j = 0; j < 4; ++j) acc[i][j] = (f32x4){0.f, 0.f, 0.f, 0.f};

  for (int k0 = 0; k0 < K; k0 += BK) {
#pragma unroll
    for (int r = 0; r < 2; ++r) {
      int arow = bm + wave * 32 + r * 16 + lrow;
      if (arow >= M) arow = M - 1;  // clamp: dup loads, masked at store
      gl_lds16(A + (size_t)arow * K + k0 + lcol, &As[wave * 32 + r * 16][0]);
      int brow = bn + wave * 32 + r * 16 + lrow;  // always < Nn (Nn%128==0)
      gl_lds16(BT + (size_t)brow * K + k0 + lcol, &Bs[wave * 32 + r * 16][0]);
    }
    __syncthreads();
    const int fr = lane & 15, kg = (lane >> 4) * 8;
    bf16x8 af[4], bfr[4];
#pragma unroll
    for (int i = 0; i < 4; ++i) {
      af[i] = *(const bf16x8*)&As[wm + i * 16 + fr][kg];
      bfr[i] = *(const bf16x8*)&Bs[wn + i * 16 + fr][kg];
    }
#pragma unroll
    for (int i = 0; i < 4; ++i)
#pragma unroll
      for (int j = 0; j < 4; ++j)
        acc[i][j] = __builtin_amdgcn_mfma_f32_16x16x32_bf16(af[i], bfr[j],
                                                            acc[i][j], 0, 0, 0);
    __syncthreads();
  }

  const int fr = lane & 15, rg = (lane >> 4) * 4;
#pragma unroll
  for (int j = 0; j < 4; ++j) {
    int col = bn + wn + j * 16 + fr;
    float bv = bias[col];
#pragma unroll
    for (int i = 0; i < 4; ++i) {
#pragma unroll
      for (int r = 0; r < 4; ++r) {
        int row = bm + wm + i * 16 + rg + r;
        if (row < M)
          C[(size_t)row * Nn + col] = (OutT)(acc[i][j][r] + bv);
      }
    }
  }
}

// ---------------------- LDS-tiled depthwise 3x3x3 pool + LN (one t-plane/blk)
// grid (T0, 128), 256 threads. Stages 3 input planes (3x196 tokens x 96ch)
// into LDS, computes oH*oW output rows with full 27x reuse.
__global__ __launch_bounds__(256) void pool_ln_tiled(
    const bf16* __restrict__ qkv, const float* __restrict__ pwT,
    const float* __restrict__ g, const float* __restrict__ bt,
    bf16* __restrict__ outp, int which, int sHW, int oW, int Lout) {
  __shared__ __align__(16) bf16 in_s[3][196][96];  // 112.9 KB
  __shared__ float pwl[2592];                      // 27 x 96

  const int tid = threadIdx.x;
  const int wv = tid >> 6, x = tid & 63;
  const int bh = blockIdx.y;
  const int b = bh >> 3, h = bh & 7;
  const int t = blockIdx.x;
  const bf16* base = qkv + (size_t)b * N_ * 2304 + which * 768 + h * 96;

  for (int i = tid; i < 2592; i += 256) pwl[i] = pwT[i];

  // ---- stage valid t-planes (each: 196 tokens x 96ch = 2352 x uint4) ----
  for (int kt = 0; kt < 3; ++kt) {
    int it = t + kt - 1;
    if (it < 0 || it >= T0_) continue;
    const bf16* pb = base + (size_t)(1 + it * 196) * 2304;
    for (int c = tid; c < 2352; c += 256) {
      int tok = c / 12, seg = c % 12;
      *(uint4*)&in_s[kt][tok][seg * 8] =
          *(const uint4*)(pb + (size_t)tok * 2304 + seg * 8);
    }
  }
  __syncthreads();

  const int R = oW * oW;  // 196 (q) or 49 (kv)
  for (int r = wv; r < R; r += 4) {
    int oh = r / oW, ow = r % oW;
    float v0 = 0.f, v1 = 0.f;
#pragma unroll
    for (int kt = 0; kt < 3; ++kt) {
      int it = t + kt - 1;
      if (it < 0 || it >= T0_) continue;
      for (int kh = 0; kh < 3; ++kh) {
        int ih = oh * sHW + kh - 1;
        if (ih < 0 || ih >= H0_) continue;
        for (int kw = 0; kw < 3; ++kw) {
          int iw = ow * sHW + kw - 1;
          if (iw < 0 || iw >= W0_) continue;
          const bf16* ip = &in_s[kt][ih * 14 + iw][0];
          int widx = (kt * 3 + kh) * 3 + kw;
          v0 += (float)ip[x] * pwl[widx * 96 + x];
          if (x < 32) v1 += (float)ip[x + 64] * pwl[widx * 96 + x + 64];
        }
      }
    }
    // LN over 96 channels (wave-wide shuffle reduce)
    float s = v0 + (x < 32 ? v1 : 0.f);
    float s2 = v0 * v0 + (x < 32 ? v1 * v1 : 0.f);
    for (int off = 32; off > 0; off >>= 1) {
      s += __shfl_down(s, off);
      s2 += __shfl_down(s2, off);
    }
    s = __shfl(s, 0);
    s2 = __shfl(s2, 0);
    float mean = s * (1.f / 96.f);
    float var = s2 * (1.f / 96.f) - mean * mean;
    float rstd = rsqrtf(var + 1e-5f);
    int orow = 1 + t * R + r;
    size_t ob = ((size_t)bh * Lout + orow) * 96;
    outp[ob + x] = __float2bfloat16((v0 - mean) * rstd * g[x] + bt[x]);
    if (x < 32)
      outp[ob + x + 64] =
          __float2bfloat16((v1 - mean) * rstd * g[x + 64] + bt[x + 64]);
  }

  // ---- cls token (orow 0): t==0 block, wave 0 ----
  if (t == 0 && wv == 0) {
    float v0 = (float)base[x];
    float v1 = (x < 32) ? (float)base[x + 64] : 0.f;
    float s = v0 + (x < 32 ? v1 : 0.f);
    float s2 = v0 * v0 + (x < 32 ? v1 * v1 : 0.f);
    for (int off = 32; off > 0; off >>= 1) {
      s += __shfl_down(s, off);
      s2 += __shfl_down(s2, off);
    }
    s = __shfl(s, 0);
    s2 = __shfl(s2, 0);
    float mean = s * (1.f / 96.f);
    float var = s2 * (1.f / 96.f) - mean * mean;
    float rstd = rsqrtf(var + 1e-5f);
    size_t ob = (size_t)bh * Lout * 96;
    outp[ob + x] = __float2bfloat16((v0 - mean) * rstd * g[x] + bt[x]);
    if (x < 32)
      outp[ob + x + 64] =
          __float2bfloat16((v1 - mean) * rstd * g[x + 64] + bt[x + 64]);
  }
}

// ------------------------------------------------- MFMA flash attention
// grid (25, 128): 64 q rows per block, one (b,h) per blockIdx.y. 256 thr.
__global__ __launch_bounds__(256) void attn_fused(
    const bf16* __restrict__ qp, const bf16* __restrict__ kp,
    const bf16* __restrict__ vT, const float* __restrict__ rph,
    const float* __restrict__ rpw, const float* __restrict__ rpt,
    bf16* __restrict__ aout) {
  __shared__ __align__(16) bf16 Qs[64][104];   // pad 96->104 (16B-aligned rows)
  __shared__ __align__(16) bf16 Ks[64][104];
  __shared__ __align__(16) bf16 Vt[96][72];    // V transposed [d][key]
  __shared__ __align__(16) bf16 Ps[4][16][72]; // per-wave P tile
  __shared__ float relb[64][24];               // t:0..7 h:8..14 w:16..22

  const int tid = threadIdx.x;
  const int wv = tid >> 6, lane = tid & 63;
  const int col = lane & 15, quad = lane >> 4;
  const int bh = blockIdx.y;
  const int b = bh >> 3, h = bh & 7;
  const int q0 = blockIdx.x * 64;
  const bf16* qb = qp + (size_t)bh * N_ * HD_;
  const bf16* kb = kp + (size_t)bh * LK_ * HD_;
  const bf16* vTb = vT + (size_t)bh * HD_ * LKP_;
  const float scale = 0.102062072615966f;  // 96^-0.5

  // ---- stage Q tile (64 x 96) ----
  for (int c = tid; c < 768; c += 256) {  // 768 chunks of 8 elems
    int row = c / 12, seg = c % 12;
    int p = q0 + row;
    if (p >= N_) p = N_ - 1;
    uint4 v = *(const uint4*)(qb + (size_t)p * HD_ + seg * 8);
    *(uint4*)&Qs[row][seg * 8] = v;
  }
  __syncthreads();

  // ---- rel-pos dot tables: 22 per q row ----
  for (int t = tid; t < 64 * 22; t += 256) {
    int qr = t / 22, j = t % 22;
    int p = q0 + qr;
    if (p >= 1 && p < N_) {
      int pos = p - 1;
      int qt = pos / 196, rr = pos % 196;
      int qh = rr / 14, qw = rr % 14;
      const float* tab;
      int slot;
      if (j < 8) { tab = rpt + (size_t)(qt - j + 7) * HD_; slot = j; }
      else if (j < 15) { int kh = j - 8; tab = rph + (size_t)(qh - 2 * kh + 12) * HD_; slot = j; }
      else { int kw = j - 15; tab = rpw + (size_t)(qw - 2 * kw + 12) * HD_; slot = 16 + kw; }
      float acc = 0.f;
      for (int d = 0; d < HD_; ++d) acc += (float)Qs[qr][d] * tab[d];
      relb[qr][slot] = acc;
    }
  }

  // ---- flash state (4 q rows per lane: row = wv*16 + quad*4 + r) ----
  float mrun[4] = {-1e30f, -1e30f, -1e30f, -1e30f};
  float lrun[4] = {0.f, 0.f, 0.f, 0.f};
  f32x4 oacc[6];
#pragma unroll
  for (int dt = 0; dt < 6; ++dt) oacc[dt] = (f32x4){0.f, 0.f, 0.f, 0.f};

  for (int kt_i = 0; kt_i < 7; ++kt_i) {
    const int kt0 = kt_i * 64;
    __syncthreads();  // prior reads of Ks/Vt done; relb visible (iter 0)
    // ---- stage K (64x96) rows; V^T tile (96 d x 64 keys) from global vT ----
    for (int c = tid; c < 768; c += 256) {
      int row = c / 12, seg = c % 12;
      int key = kt0 + row;
      if (key >= LK_) key = LK_ - 1;
      *(uint4*)&Ks[row][seg * 8] =
          *(const uint4*)(kb + (size_t)key * HD_ + seg * 8);
    }
    for (int c = tid; c < 768; c += 256) {
      int d = c >> 3, seg = c & 7;
      *(uint4*)&Vt[d][seg * 8] =
          *(const uint4*)(vTb + (size_t)d * LKP_ + kt0 + seg * 8);
    }
    __syncthreads();

    // ---- S = Q K^T : wave wv computes rows [wv*16, wv*16+16) x 64 keys ----
    f32x4 sacc[4];
#pragma unroll
    for (int jt = 0; jt < 4; ++jt) sacc[jt] = (f32x4){0.f, 0.f, 0.f, 0.f};
#pragma unroll
    for (int ks_ = 0; ks_ < 3; ++ks_) {
      bf16x8 aq = *(const bf16x8*)&Qs[wv * 16 + col][ks_ * 32 + quad * 8];
#pragma unroll
      for (int jt = 0; jt < 4; ++jt) {
        bf16x8 bk = *(const bf16x8*)&Ks[jt * 16 + col][ks_ * 32 + quad * 8];
        sacc[jt] = __builtin_amdgcn_mfma_f32_16x16x32_bf16(aq, bk, sacc[jt], 0, 0, 0);
      }
    }

    // ---- scale + rel-pos bias + validity ----
    float sv[4][4];  // [jt][reg]
#pragma unroll
    for (int jt = 0; jt < 4; ++jt) {
      int kglob = kt0 + jt * 16 + col;
      bool kvalid = (kglob < LK_);
      int kbod = (kglob >= 1) ? kglob - 1 : 0;
      int kt_ = kbod / 49, krem = kbod % 49;
      int kh_ = krem / 7, kw_ = krem % 7;
#pragma unroll
      for (int r = 0; r < 4; ++r) {
        int qr = wv * 16 + quad * 4 + r;
        int p = q0 + qr;
        float s = sacc[jt][r] * scale;
        if (kvalid && kglob >= 1 && p >= 1 && p < N_)
          s += relb[qr][kt_] + relb[qr][8 + kh_] + relb[qr][16 + kw_];
        if (!kvalid) s = -1e30f;
        sv[jt][r] = s;
      }
    }

    // ---- online softmax (row spread over 16-lane cluster) ----
    float pexp[4][4];
#pragma unroll
    for (int r = 0; r < 4; ++r) {
      float pm = fmaxf(fmaxf(sv[0][r], sv[1][r]), fmaxf(sv[2][r], sv[3][r]));
#pragma unroll
      for (int mk = 1; mk < 16; mk <<= 1) pm = fmaxf(pm, __shfl_xor(pm, mk));
      float mn = fmaxf(mrun[r], pm);
      float alpha = __expf(mrun[r] - mn);
      mrun[r] = mn;
      float rs = 0.f;
#pragma unroll
      for (int jt = 0; jt < 4; ++jt) {
        float e = __expf(sv[jt][r] - mn);
        pexp[jt][r] = e;
        rs += e;
      }
#pragma unroll
      for (int mk = 1; mk < 16; mk <<= 1) rs += __shfl_xor(rs, mk);
      lrun[r] = lrun[r] * alpha + rs;
#pragma unroll
      for (int dt = 0; dt < 6; ++dt) {
        oacc[dt][r] *= alpha;
      }
    }

    // ---- P (C-layout) -> LDS -> A-layout ----
#pragma unroll
    for (int jt = 0; jt < 4; ++jt)
#pragma unroll
      for (int r = 0; r < 4; ++r)
        Ps[wv][quad * 4 + r][jt * 16 + col] = __float2bfloat16(pexp[jt][r]);
    // wave-private LDS region: compiler's lgkmcnt wait orders write->read

    // ---- O += P V ----
#pragma unroll
    for (int ks_ = 0; ks_ < 2; ++ks_) {
      bf16x8 ap = *(const bf16x8*)&Ps[wv][col][ks_ * 32 + quad * 8];
#pragma unroll
      for (int dt = 0; dt < 6; ++dt) {
        bf16x8 bv = *(const bf16x8*)&Vt[dt * 16 + col][ks_ * 32 + quad * 8];
        oacc[dt] = __builtin_amdgcn_mfma_f32_16x16x32_bf16(ap, bv, oacc[dt], 0, 0, 0);
      }
    }
  }

  // ---- epilogue: O/l + residual q, store bf16 ----
#pragma unroll
  for (int r = 0; r < 4; ++r) {
    int qr = wv * 16 + quad * 4 + r;
    int p = q0 + qr;
    if (p >= N_) continue;
    float inv = 1.f / lrun[r];
#pragma unroll
    for (int dt = 0; dt < 6; ++dt) {
      int d = dt * 16 + col;
      float val = oacc[dt][r] * inv;
      if (p >= 1) val += (float)Qs[qr][d];
      aout[((size_t)b * N_ + p) * DIM_ + h * HD_ + d] = __float2bfloat16(val);
    }
  }
}

// ------------------------------------------------------------------- launch
extern "C" void kernel_launch(void* const* d_in, const int* in_sizes, int n_in,
                              void* d_out, int out_size, void* d_ws,
                              size_t ws_size, hipStream_t stream) {
  (void)in_sizes; (void)n_in; (void)out_size; (void)ws_size;
  const float* x      = (const float*)d_in[0];
  const float* qkv_w  = (const float*)d_in[1];
  const float* qkv_b  = (const float*)d_in[2];
  const float* pool_q = (const float*)d_in[3];
  const float* pool_k = (const float*)d_in[4];
  const float* pool_v = (const float*)d_in[5];
  const float* ln_q_g = (const float*)d_in[6];
  const float* ln_q_b = (const float*)d_in[7];
  const float* ln_k_g = (const float*)d_in[8];
  const float* ln_k_b = (const float*)d_in[9];
  const float* ln_v_g = (const float*)d_in[10];
  const float* ln_v_b = (const float*)d_in[11];
  const float* rph    = (const float*)d_in[12];
  const float* rpw    = (const float*)d_in[13];
  const float* rpt    = (const float*)d_in[14];
  const float* proj_w = (const float*)d_in[15];
  const float* proj_b = (const float*)d_in[16];

  char* ws = (char*)d_ws;
  bf16* wt_qkv  = (bf16*)(ws);                  // 2304x768 bf16   (3.54 MB)
  bf16* wt_proj = (bf16*)(ws + 3538944);        // 768x768 bf16    (1.18 MB)
  bf16* xb      = (bf16*)(ws + 4718592);        // 25104x768 bf16  (38.6 MB)
  bf16* aout    = xb;                           // reuse: xb dead after gemm#1
  bf16* qkv     = (bf16*)(ws + 43278336);       // 25104x2304 bf16 (115.7 MB)
  bf16* qpoolb  = (bf16*)(ws + 158957568);      // 128x1569x96 bf16 (38.6 MB)
  bf16* kpoolb  = (bf16*)(ws + 197517312);      // 128x393x96 bf16  (9.7 MB)
  bf16* vpoolb  = (bf16*)(ws + 207175680);      // 128x393x96 bf16  (9.7 MB)
  float* pwT    = (float*)(ws + 216834048);     // 3x27x96 fp32     (31 KB)
  bf16* vT      = (bf16*)(ws + 216865280);      // 128x96x448 bf16  (11 MB)
  float* outp   = (float*)d_out;                // fp32 output per reference

  int n4 = (B_ * N_ * DIM_) / 4;
  cvt_f32_bf16<<<(n4 + 255) / 256, 256, 0, stream>>>(x, xb, n4);
  transpose_f32_bf16<<<dim3(72, 24), dim3(32, 8), 0, stream>>>(qkv_w, wt_qkv, 768, 2304);
  transpose_f32_bf16<<<dim3(24, 24), dim3(32, 8), 0, stream>>>(proj_w, wt_proj, 768, 768);
  prep_pw<<<11, 256, 0, stream>>>(pool_q, pool_k, pool_v, pwT);

  gemm_bt<bf16><<<dim3(18, 197), 256, 0, stream>>>(xb, wt_qkv, qkv_b, qkv,
                                                   B_ * N_, 3 * DIM_, DIM_);

  pool_ln_tiled<<<dim3(8, 128), 256, 0, stream>>>(qkv, pwT, ln_q_g, ln_q_b,
                                                  qpoolb, 0, 1, 14, N_);
  pool_ln_tiled<<<dim3(8, 128), 256, 0, stream>>>(qkv, pwT + 2592, ln_k_g,
                                                  ln_k_b, kpoolb, 1, 2, 7, LK_);
  pool_ln_tiled<<<dim3(8, 128), 256, 0, stream>>>(qkv, pwT + 5184, ln_v_g,
                                                  ln_v_b, vpoolb, 2, 2, 7, LK_);

  transpose_v<<<dim3(14, 3, 128), dim3(32, 8), 0, stream>>>(vpoolb, vT);

  attn_fused<<<dim3(25, 128), 256, 0, stream>>>(qpoolb, kpoolb, vT, rph,
                                                rpw, rpt, aout);

  gemm_bt<float><<<dim3(6, 197), 256, 0, stream>>>(aout, wt_proj, proj_b, outp,
                                                   B_ * N_, DIM_, DIM_);
}